// Round 7
// baseline (3434.596 us; speedup 1.0000x reference)
//
#include <hip/hip_runtime.h>

typedef _Float16 half8 __attribute__((ext_vector_type(8)));
typedef _Float16 half4 __attribute__((ext_vector_type(4)));
typedef float floatx4 __attribute__((ext_vector_type(4)));
typedef unsigned uintx4 __attribute__((ext_vector_type(4)));
typedef unsigned long long u64;

#define T_STEPS 512
#define IN_DIM 256
#define HID 512
#define RING 8

// ---- R11: R9's tagged-word protocol x R10's frag-linear layout ----
// Tagged element (R,C) of a 64x512 snapshot, u32 = (tag<<16)|fp16bits, at u32:
//   (R>>4)*8192 + (C>>5)*512 + ((R&15)+16*((C>>3)&3))*8 + (C&7)
// Consumer lane reads its own 32B slot per fragment (2 coalesced dwordx4).
// Producers store tagged u64 pairs fire-and-forget (no drains, no data flags).
// tag(step s) = s+1; seeds stamped tag 0. Progress flags remain ONLY as the
// h0-ring throttle (hidden polls) and the epilogue sentinel.

__device__ inline float sig_f(float x) { return 1.f / (1.f + __expf(-x)); }
__device__ inline float tanh_f(float x) {
  float t = __expf(-2.f * fabsf(x));
  return copysignf((1.f - t) / (1.f + t), x);
}
__device__ inline unsigned umin_(unsigned a, unsigned b) { return a < b ? a : b; }
__device__ inline unsigned fpbits(float x) {
  return (unsigned)__builtin_bit_cast(unsigned short, (_Float16)x);
}
__device__ inline unsigned tagoff(int R, int C) {  // u32 units within snapshot
  return (unsigned)((R >> 4) * 8192 + (C >> 5) * 512 +
                    ((R & 15) + 16 * ((C >> 3) & 3)) * 8 + (C & 7));
}

// Tagged poll-load of one wave-region (16 frags x 32B/lane), coalesced.
// Retries until every u64's low-word tag >= exp (tags monotone per slot).
__device__ inline void tagpoll16c(const char* b, unsigned exp, half8 (&f)[16]) {
  const unsigned expw = exp << 16;
  const char* b0 = b;
  const char* b1 = b + 4096;
  const char* b2 = b + 8192;
  const char* b3 = b + 12288;
  const char* b4 = b + 16384;
  const char* b5 = b + 20480;
  const char* b6 = b + 24576;
  const char* b7 = b + 28672;
  uintx4 u[32];
  int it = 0;
  for (;;) {
    floatx4 t0, t1, t2, t3, t4, t5, t6, t7, t8, t9, t10, t11, t12, t13, t14, t15;
    floatx4 s0, s1, s2, s3, s4, s5, s6, s7, s8, s9, s10, s11, s12, s13, s14, s15;
    asm volatile(
        "global_load_dwordx4 %0, %16, off sc0 sc1\n\t"
        "global_load_dwordx4 %1, %16, off offset:16 sc0 sc1\n\t"
        "global_load_dwordx4 %2, %16, off offset:2048 sc0 sc1\n\t"
        "global_load_dwordx4 %3, %16, off offset:2064 sc0 sc1\n\t"
        "global_load_dwordx4 %4, %17, off sc0 sc1\n\t"
        "global_load_dwordx4 %5, %17, off offset:16 sc0 sc1\n\t"
        "global_load_dwordx4 %6, %17, off offset:2048 sc0 sc1\n\t"
        "global_load_dwordx4 %7, %17, off offset:2064 sc0 sc1\n\t"
        "global_load_dwordx4 %8, %18, off sc0 sc1\n\t"
        "global_load_dwordx4 %9, %18, off offset:16 sc0 sc1\n\t"
        "global_load_dwordx4 %10, %18, off offset:2048 sc0 sc1\n\t"
        "global_load_dwordx4 %11, %18, off offset:2064 sc0 sc1\n\t"
        "global_load_dwordx4 %12, %19, off sc0 sc1\n\t"
        "global_load_dwordx4 %13, %19, off offset:16 sc0 sc1\n\t"
        "global_load_dwordx4 %14, %19, off offset:2048 sc0 sc1\n\t"
        "global_load_dwordx4 %15, %19, off offset:2064 sc0 sc1"
        : "=&v"(t0), "=&v"(t1), "=&v"(t2), "=&v"(t3),
          "=&v"(t4), "=&v"(t5), "=&v"(t6), "=&v"(t7),
          "=&v"(t8), "=&v"(t9), "=&v"(t10), "=&v"(t11),
          "=&v"(t12), "=&v"(t13), "=&v"(t14), "=&v"(t15)
        : "v"(b0), "v"(b1), "v"(b2), "v"(b3)
        : "memory");
    asm volatile(
        "global_load_dwordx4 %0, %16, off sc0 sc1\n\t"
        "global_load_dwordx4 %1, %16, off offset:16 sc0 sc1\n\t"
        "global_load_dwordx4 %2, %16, off offset:2048 sc0 sc1\n\t"
        "global_load_dwordx4 %3, %16, off offset:2064 sc0 sc1\n\t"
        "global_load_dwordx4 %4, %17, off sc0 sc1\n\t"
        "global_load_dwordx4 %5, %17, off offset:16 sc0 sc1\n\t"
        "global_load_dwordx4 %6, %17, off offset:2048 sc0 sc1\n\t"
        "global_load_dwordx4 %7, %17, off offset:2064 sc0 sc1\n\t"
        "global_load_dwordx4 %8, %18, off sc0 sc1\n\t"
        "global_load_dwordx4 %9, %18, off offset:16 sc0 sc1\n\t"
        "global_load_dwordx4 %10, %18, off offset:2048 sc0 sc1\n\t"
        "global_load_dwordx4 %11, %18, off offset:2064 sc0 sc1\n\t"
        "global_load_dwordx4 %12, %19, off sc0 sc1\n\t"
        "global_load_dwordx4 %13, %19, off offset:16 sc0 sc1\n\t"
        "global_load_dwordx4 %14, %19, off offset:2048 sc0 sc1\n\t"
        "global_load_dwordx4 %15, %19, off offset:2064 sc0 sc1\n\t"
        "s_waitcnt vmcnt(0)"
        : "=&v"(s0), "=&v"(s1), "=&v"(s2), "=&v"(s3),
          "=&v"(s4), "=&v"(s5), "=&v"(s6), "=&v"(s7),
          "=&v"(s8), "=&v"(s9), "=&v"(s10), "=&v"(s11),
          "=&v"(s12), "=&v"(s13), "=&v"(s14), "=&v"(s15)
        : "v"(b4), "v"(b5), "v"(b6), "v"(b7)
        : "memory");
    __builtin_amdgcn_sched_barrier(0);  // no consumer hoists above the wait
    u[0] = __builtin_bit_cast(uintx4, t0);   u[1] = __builtin_bit_cast(uintx4, t1);
    u[2] = __builtin_bit_cast(uintx4, t2);   u[3] = __builtin_bit_cast(uintx4, t3);
    u[4] = __builtin_bit_cast(uintx4, t4);   u[5] = __builtin_bit_cast(uintx4, t5);
    u[6] = __builtin_bit_cast(uintx4, t6);   u[7] = __builtin_bit_cast(uintx4, t7);
    u[8] = __builtin_bit_cast(uintx4, t8);   u[9] = __builtin_bit_cast(uintx4, t9);
    u[10] = __builtin_bit_cast(uintx4, t10); u[11] = __builtin_bit_cast(uintx4, t11);
    u[12] = __builtin_bit_cast(uintx4, t12); u[13] = __builtin_bit_cast(uintx4, t13);
    u[14] = __builtin_bit_cast(uintx4, t14); u[15] = __builtin_bit_cast(uintx4, t15);
    u[16] = __builtin_bit_cast(uintx4, s0);  u[17] = __builtin_bit_cast(uintx4, s1);
    u[18] = __builtin_bit_cast(uintx4, s2);  u[19] = __builtin_bit_cast(uintx4, s3);
    u[20] = __builtin_bit_cast(uintx4, s4);  u[21] = __builtin_bit_cast(uintx4, s5);
    u[22] = __builtin_bit_cast(uintx4, s6);  u[23] = __builtin_bit_cast(uintx4, s7);
    u[24] = __builtin_bit_cast(uintx4, s8);  u[25] = __builtin_bit_cast(uintx4, s9);
    u[26] = __builtin_bit_cast(uintx4, s10); u[27] = __builtin_bit_cast(uintx4, s11);
    u[28] = __builtin_bit_cast(uintx4, s12); u[29] = __builtin_bit_cast(uintx4, s13);
    u[30] = __builtin_bit_cast(uintx4, s14); u[31] = __builtin_bit_cast(uintx4, s15);
    unsigned mn = 0xffffffffu;
#pragma unroll
    for (int k = 0; k < 32; ++k) {
      mn = umin_(mn, u[k].x);
      mn = umin_(mn, u[k].z);
    }
    if (__all((int)(mn >= expw))) break;
    if (++it > 3) __builtin_amdgcn_s_sleep(1);
  }
#pragma unroll
  for (int c = 0; c < 16; ++c) {
    unsigned q0 = (u[2 * c].x & 0xffffu) | (u[2 * c].y << 16);
    unsigned q1 = (u[2 * c].z & 0xffffu) | (u[2 * c].w << 16);
    unsigned q2 = (u[2 * c + 1].x & 0xffffu) | (u[2 * c + 1].y << 16);
    unsigned q3 = (u[2 * c + 1].z & 0xffffu) | (u[2 * c + 1].w << 16);
    uintx4 qq = {q0, q1, q2, q3};
    f[c] = __builtin_bit_cast(half8, qq);
  }
}

// Epilogue-only: lane i min-reduces block i's 4 per-wave sub-flags (16B).
__device__ inline void waitf4(const unsigned* fg, unsigned tg) {
  const unsigned* p = fg + (threadIdx.x & 63) * 32;
  int it = 0;
  for (;;) {
    floatx4 t;
    asm volatile("global_load_dwordx4 %0, %1, off sc0 sc1\n\t"
                 "s_waitcnt vmcnt(0)"
                 : "=&v"(t) : "v"(p) : "memory");
    uintx4 u = __builtin_bit_cast(uintx4, t);
    unsigned m = umin_(umin_(u.x, u.y), umin_(u.z, u.w));
    if (__all((int)(m >= tg))) return;
    if (++it > 4) __builtin_amdgcn_s_sleep(1);
  }
}

__device__ inline floatx4 mfma16(half8 a, half8 b, floatx4 c) {
  return __builtin_amdgcn_mfma_f32_16x16x32_f16(a, b, c, 0, 0, 0);
}

__global__ void init_kernel(const float* __restrict__ x, const float* __restrict__ hc,
                            _Float16* __restrict__ x16, unsigned* __restrict__ h0b,
                            unsigned* __restrict__ h1b, unsigned* __restrict__ flagbase) {
  size_t i = (size_t)blockIdx.x * blockDim.x + threadIdx.x;
  size_t stride = (size_t)gridDim.x * blockDim.x;
  // x -> frag-linear fp16 (R10-proven): chunk n=(t*64+row)*32+cc -> cols 8cc..
  const size_t nch = (size_t)T_STEPS * 64 * 32;
  for (size_t n = i; n < nch; n += stride) {
    size_t tr = n >> 5;
    int cc = (int)(n & 31);
    int row = (int)(tr & 63);
    size_t t = tr >> 6;
    const float* src = x + (tr * 256 + (size_t)cc * 8);
    floatx4 v0 = *(const floatx4*)src;
    floatx4 v1 = *(const floatx4*)(src + 4);
    half8 h;
    h[0] = (_Float16)v0.x; h[1] = (_Float16)v0.y; h[2] = (_Float16)v0.z; h[3] = (_Float16)v0.w;
    h[4] = (_Float16)v1.x; h[5] = (_Float16)v1.y; h[6] = (_Float16)v1.z; h[7] = (_Float16)v1.w;
    _Float16* dstp = x16 + t * 16384 + (size_t)(row >> 4) * 4096 +
                     (size_t)(cc >> 2) * 512 + (size_t)((row & 15) + 16 * (cc & 3)) * 8;
    *(half8*)dstp = h;
  }
  // Stamp ALL tagged h words to tag 0 (seed data in h0 slot 7 / h1 parity 1).
  const size_t ntag = 262144 + 65536;
  for (size_t idx = i; idx < ntag; idx += stride) {
    unsigned v = 0;
    unsigned* dst;
    if (idx < 262144) {
      int slot = (int)(idx >> 15);
      int w = (int)(idx & 32767);
      int R = w >> 9, C = w & 511;
      if (slot == RING - 1) v = fpbits(hc[(size_t)R * 512 + C]);
      dst = h0b + (size_t)slot * 32768 + tagoff(R, C);
    } else {
      size_t j = idx - 262144;
      int par = (int)(j >> 15);
      int w = (int)(j & 32767);
      int R = w >> 9, C = w & 511;
      if (par == 1) v = fpbits(hc[32768 + (size_t)R * 512 + C]);
      dst = h1b + (size_t)par * 32768 + tagoff(R, C);
    }
    __hip_atomic_store(dst, v, __ATOMIC_RELAXED, __HIP_MEMORY_SCOPE_AGENT);
  }
  if (i < 4096) {  // zero both flag arrays (2 x 8192 B contiguous)
    __hip_atomic_store(flagbase + i, 0u, __ATOMIC_RELAXED, __HIP_MEMORY_SCOPE_AGENT);
  }
}

__global__ __launch_bounds__(256, 1) void lstm_kernel(
    const _Float16* __restrict__ x16, unsigned* __restrict__ h0b, unsigned* __restrict__ h1b,
    unsigned* __restrict__ flags0, unsigned* __restrict__ flags1,
    const float* __restrict__ W_ih0, const float* __restrict__ W_hh0,
    const float* __restrict__ b_ih0, const float* __restrict__ b_hh0,
    const float* __restrict__ W_ih1, const float* __restrict__ W_hh1,
    const float* __restrict__ b_ih1, const float* __restrict__ b_hh1,
    const float* __restrict__ W_out, const float* __restrict__ b_out,
    const float* __restrict__ hc, float* __restrict__ out) {
  __shared__ __align__(16) _Float16 wlds[32 * 1032];

  const int bq = blockIdx.x;
  const bool isL0 = bq < 64;
  const int q = isL0 ? bq : bq - 64;
  const int col0 = q * 8;
  const int Ka = isL0 ? IN_DIM : HID;
  const int K = Ka + HID;
  const int WP = K + 8;
  const int layer = isL0 ? 0 : 1;
  const float* Wa = isL0 ? W_ih0 : W_ih1;
  const float* Wb = isL0 ? W_hh0 : W_hh1;
  const float* bia = isL0 ? b_ih0 : b_ih1;
  const float* bib = isL0 ? b_hh0 : b_hh1;

  for (int idx = threadIdx.x; idx < 32 * K; idx += 256) {
    int r = idx / K;
    int k = idx - r * K;
    int g = r >> 3, j = r & 7;
    int grow = g * HID + col0 + j;  // PyTorch gate order i,f,g,o
    float w = (k < Ka) ? Wa[(size_t)grow * Ka + k] : Wb[(size_t)grow * HID + (k - Ka)];
    wlds[r * WP + k] = (_Float16)w;
  }
  __syncthreads();

  const int lane = threadIdx.x & 63;
  const int wv = threadIdx.x >> 6;   // 0..3
  const int lrow = lane & 15;
  const int kq = (lane >> 4) * 8;
  const _Float16* wrow0 = wlds + lrow * WP;
  const _Float16* wrow1 = wlds + (16 + lrow) * WP;

  // Recurrent-half B fragments in registers/AGPRs (R2/R3-proven).
  half8 breg0[16], breg1[16];
#pragma unroll
  for (int c = 0; c < 16; ++c) {
    breg0[c] = *(const half8*)(wrow0 + Ka + c * 32 + kq);
    breg1[c] = *(const half8*)(wrow1 + Ka + c * 32 + kq);
  }

  // Register-gate-phase constants (R8-proven mapping).
  const int bsel = lrow >> 3;
  const int jc = lrow & 7;
  const int rbase = wv * 16 + ((lane >> 4) << 2) + 2 * bsel;
  const int colg = col0 + jc;
  const float bi_ = bia[colg] + bib[colg];
  const float bf_ = bia[HID + colg] + bib[HID + colg];
  const float bg_ = bia[2 * HID + colg] + bib[2 * HID + colg];
  const float bo_ = bia[3 * HID + colg] + bib[3 * HID + colg];
  float cst0 = hc[(size_t)(2 + layer) * 32768 + (size_t)(rbase + 0) * HID + colg];
  float cst1 = hc[(size_t)(2 + layer) * 32768 + (size_t)(rbase + 1) * HID + colg];

  unsigned* myflag = (isL0 ? flags0 : flags1) + q * 32 + wv;
  const unsigned* pf0 = flags0 + lane * 32 + wv;  // L0 throttle gathers
  const unsigned* pf1 = flags1 + lane * 32 + wv;

  // Frag-linear tagged offsets (bytes): read base within snapshot.
  const size_t rdb = (size_t)wv * 32768 + (size_t)lane * 32;
  // Store slot (u32 units within snapshot).
  const unsigned stoff = (unsigned)(wv * 8192 + (q >> 2) * 512 +
                                    ((rbase & 15) + ((q & 3) << 4)) * 8 + jc);

  for (int t = 0; t < T_STEPS; ++t) {
    floatx4 acc0 = {0.f, 0.f, 0.f, 0.f};
    floatx4 acc1 = {0.f, 0.f, 0.f, 0.f};
    unsigned* dstu;
    half8 f[16];

    if (isL0) {
      // Pre-issue throttle samples; hidden under X phase + tagpoll.
      unsigned f0v = 0xffffffffu, f1v = 0xffffffffu;
      const bool chk = (t >= 7);
      if (chk) {
        asm volatile("global_load_dword %0, %2, off sc0 sc1\n\t"
                     "global_load_dword %1, %3, off sc0 sc1"
                     : "=&v"(f0v), "=&v"(f1v)
                     : "v"(pf0), "v"(pf1) : "memory");
      }
      // X phase (plain frag-linear loads, no cross-block dep).
      const _Float16* xw = x16 + (size_t)t * 16384 + (size_t)wv * 4096 + (size_t)lane * 8;
#pragma unroll
      for (int c = 0; c < 8; ++c) {
        half8 a = *(const half8*)(xw + c * 512);
        half8 b0v = *(const half8*)(wrow0 + c * 32 + kq);
        half8 b1v = *(const half8*)(wrow1 + c * 32 + kq);
        acc0 = mfma16(a, b0v, acc0);
        acc1 = mfma16(a, b1v, acc1);
      }
      // Recurrent: tagged poll of h0[t-1] (tag t) — data IS the readiness.
      tagpoll16c((const char*)(h0b + (size_t)((t - 1) & (RING - 1)) * 32768) + rdb,
                 (unsigned)t, f);
      // Ring throttle before overwriting slot t&7 (pre-issued samples now done).
      if (chk) {
        asm volatile("s_waitcnt vmcnt(0)" ::: "memory");
        __builtin_amdgcn_sched_barrier(0);
        const unsigned need0 = (unsigned)(t - 6);
        const unsigned need1 = (t >= 8) ? (unsigned)(t - 7) : 0u;
        int it = 0;
        while (!__all((int)((f0v >= need0) & (f1v >= need1)))) {
          if (++it > 2) __builtin_amdgcn_s_sleep(1);
          asm volatile("global_load_dword %0, %2, off sc0 sc1\n\t"
                       "global_load_dword %1, %3, off sc0 sc1\n\t"
                       "s_waitcnt vmcnt(0)"
                       : "=&v"(f0v), "=&v"(f1v)
                       : "v"(pf0), "v"(pf1) : "memory");
          __builtin_amdgcn_sched_barrier(0);
        }
      }
      if (lane == 0)  // progress (load-completion certificate; no drain needed)
        __hip_atomic_store(myflag, (unsigned)(t + 1), __ATOMIC_RELAXED, __HIP_MEMORY_SCOPE_AGENT);
#pragma unroll
      for (int c = 0; c < 16; ++c) {
        acc0 = mfma16(f[c], breg0[c], acc0);
        acc1 = mfma16(f[c], breg1[c], acc1);
      }
      dstu = h0b + (size_t)(t & (RING - 1)) * 32768;
    } else {
      // Phase 1: tagged poll of h0[t] (tag t+1; L0 ahead -> near-hit).
      tagpoll16c((const char*)(h0b + (size_t)(t & (RING - 1)) * 32768) + rdb,
                 (unsigned)(t + 1), f);
      if (lane == 0)  // ring release: h0[t] consumed by this wave
        __hip_atomic_store(myflag, (unsigned)(t + 1), __ATOMIC_RELAXED, __HIP_MEMORY_SCOPE_AGENT);
#pragma unroll
      for (int c = 0; c < 16; ++c) {
        half8 b0v = *(const half8*)(wrow0 + c * 32 + kq);
        half8 b1v = *(const half8*)(wrow1 + c * 32 + kq);
        acc0 = mfma16(f[c], b0v, acc0);
        acc1 = mfma16(f[c], b1v, acc1);
      }
      // Phase 2: tagged poll of h1[t-1] (tag t) — THE recurrence hop. Peer
      // stores became visible during phase 1 (~1500cy window).
      tagpoll16c((const char*)(h1b + (size_t)((t - 1) & 1) * 32768) + rdb,
                 (unsigned)t, f);
#pragma unroll
      for (int c = 0; c < 16; ++c) {
        acc0 = mfma16(f[c], breg0[c], acc0);
        acc1 = mfma16(f[c], breg1[c], acc1);
      }
      dstu = h1b + (size_t)(t & 1) * 32768;
    }

    // ---- register gate phase (R8-proven) ----
    float s00 = __shfl_xor(bsel ? (float)acc0[0] : (float)acc0[2], 8);
    float s01 = __shfl_xor(bsel ? (float)acc0[1] : (float)acc0[3], 8);
    float s10 = __shfl_xor(bsel ? (float)acc1[0] : (float)acc1[2], 8);
    float s11 = __shfl_xor(bsel ? (float)acc1[1] : (float)acc1[3], 8);
    float hv0, hv1;
    {
      float o0 = bsel ? (float)acc0[2] : (float)acc0[0];
      float o1 = bsel ? (float)acc1[2] : (float)acc1[0];
      float gi = bsel ? s00 : o0;
      float gf = bsel ? o0 : s00;
      float gg = bsel ? s10 : o1;
      float go = bsel ? o1 : s10;
      float c = sig_f(gf + bf_) * cst0 + sig_f(gi + bi_) * tanh_f(gg + bg_);
      cst0 = c;
      hv0 = sig_f(go + bo_) * tanh_f(c);
    }
    {
      float o0 = bsel ? (float)acc0[3] : (float)acc0[1];
      float o1 = bsel ? (float)acc1[3] : (float)acc1[1];
      float gi = bsel ? s01 : o0;
      float gf = bsel ? o0 : s01;
      float gg = bsel ? s11 : o1;
      float go = bsel ? o1 : s11;
      float c = sig_f(gf + bf_) * cst1 + sig_f(gi + bi_) * tanh_f(gg + bg_);
      cst1 = c;
      hv1 = sig_f(go + bo_) * tanh_f(c);
    }
    float hx0 = __shfl_xor(hv0, 1);
    float hx1 = __shfl_xor(hv1, 1);
    if ((jc & 1) == 0) {
      const unsigned tgw = (unsigned)(t + 1) << 16;
      unsigned* sb = dstu + stoff;
      unsigned lo0 = tgw | fpbits(hv0), hi0 = tgw | fpbits(hx0);
      __hip_atomic_store((u64*)sb, ((u64)hi0 << 32) | lo0,
                         __ATOMIC_RELAXED, __HIP_MEMORY_SCOPE_AGENT);
      unsigned lo1 = tgw | fpbits(hv1), hi1 = tgw | fpbits(hx1);
      __hip_atomic_store((u64*)(sb + 8), ((u64)hi1 << 32) | lo1,
                         __ATOMIC_RELAXED, __HIP_MEMORY_SCOPE_AGENT);
    }
    // Fire-and-forget: no drain, no flag, no barrier.
  }

  if (!isL0) {
    // Epilogue sentinel (the one drain in the kernel).
    asm volatile("s_waitcnt vmcnt(0)" ::: "memory");
    if (lane == 0)
      __hip_atomic_store(myflag, 1023u, __ATOMIC_RELAXED, __HIP_MEMORY_SCOPE_AGENT);
  } else {
    // Final linear: out[64,256] = h1[511] @ W_out^T + b_out (tagged reads).
    if (threadIdx.x < 64) waitf4(flags1, 1023u);
    __syncthreads();
    asm volatile("" ::: "memory");
    const int oc = q * 4 + (threadIdx.x & 3);
    const int m = threadIdx.x >> 2;
    const float* wrow = W_out + (size_t)oc * HID;
    const unsigned* hbase = h1b + 32768;  // h1[511] at parity 1, tagged
    float sum = 0.f;
#pragma unroll 4
    for (int hh = 0; hh < 64; ++hh) {
      const unsigned* cp = hbase + (size_t)(m >> 4) * 8192 + (size_t)(hh >> 2) * 512 +
                           (size_t)((m & 15) + 16 * (hh & 3)) * 8;
#pragma unroll
      for (int k = 0; k < 8; k += 2) {
        u64 d = __hip_atomic_load((const u64*)(cp + k), __ATOMIC_RELAXED,
                                  __HIP_MEMORY_SCOPE_AGENT);
        sum += (float)__builtin_bit_cast(_Float16, (unsigned short)(d & 0xffffu)) * wrow[hh * 8 + k];
        sum += (float)__builtin_bit_cast(_Float16, (unsigned short)((d >> 32) & 0xffffu)) * wrow[hh * 8 + k + 1];
      }
    }
    out[m * 256 + oc] = sum + b_out[oc];
  }
}

extern "C" void kernel_launch(void* const* d_in, const int* in_sizes, int n_in,
                              void* d_out, int out_size, void* d_ws, size_t ws_size,
                              hipStream_t stream) {
  const float* x     = (const float*)d_in[0];
  const float* hc    = (const float*)d_in[1];
  const float* W_ih0 = (const float*)d_in[2];
  const float* W_hh0 = (const float*)d_in[3];
  const float* b_ih0 = (const float*)d_in[4];
  const float* b_hh0 = (const float*)d_in[5];
  const float* W_ih1 = (const float*)d_in[6];
  const float* W_hh1 = (const float*)d_in[7];
  const float* b_ih1 = (const float*)d_in[8];
  const float* b_hh1 = (const float*)d_in[9];
  const float* W_out = (const float*)d_in[10];
  const float* b_out = (const float*)d_in[11];
  float* out = (float*)d_out;

  char* ws = (char*)d_ws;
  _Float16* x16 = (_Float16*)ws;                         // 16 MB (frag-linear)
  unsigned* h0b = (unsigned*)(ws + 16777216);            // 8 x 128 KB tagged ring
  unsigned* h1b = (unsigned*)(ws + 16777216 + 1048576);  // 2 x 128 KB tagged
  unsigned* flags0 = (unsigned*)(ws + 16777216 + 1048576 + 262144);         // 8 KB
  unsigned* flags1 = (unsigned*)(ws + 16777216 + 1048576 + 262144 + 8192);  // 8 KB

  init_kernel<<<2048, 256, 0, stream>>>(x, hc, x16, h0b, h1b, flags0);
  lstm_kernel<<<128, 256, 0, stream>>>(x16, h0b, h1b, flags0, flags1,
                                       W_ih0, W_hh0, b_ih0, b_hh0,
                                       W_ih1, W_hh1, b_ih1, b_hh1,
                                       W_out, b_out, hc, out);
}

// Round 8
// 3126.104 us; speedup vs baseline: 1.0987x; 1.0987x over previous
//
#include <hip/hip_runtime.h>

typedef _Float16 half8 __attribute__((ext_vector_type(8)));
typedef float floatx4 __attribute__((ext_vector_type(4)));
typedef unsigned uintx4 __attribute__((ext_vector_type(4)));
typedef unsigned long long u64;

#define T_STEPS 512
#define IN_DIM 256
#define HID 512
#define RING 8

// ---- R12: R10 layout/loaders (proven 1776us) + per-wave barrier-free flags
// (R8-proven) + piggybacked publish / pre-issued hidden polls.
// flags0[q*32+wv] = s  <=>  L0 block q wave wv: h0[s-1] region-wv visible.
// flags1[q*32+wv] = s  <=>  L1 block q wave wv: h0[s-1] consumed AND
//                            h1[s-2] region-wv visible (publish after the
//                            next-step ldfrag's vmcnt0, which drains stores).

__device__ inline float sig_f(float x) { return 1.f / (1.f + __expf(-x)); }
__device__ inline float tanh_f(float x) {
  float t = __expf(-2.f * fabsf(x));
  return copysignf((1.f - t) / (1.f + t), x);
}
__device__ inline unsigned umin_(unsigned a, unsigned b) { return a < b ? a : b; }

__device__ inline void cstore_pair(_Float16* p, float a, float b) {
  union { unsigned u; _Float16 h[2]; } pk;
  pk.h[0] = (_Float16)a; pk.h[1] = (_Float16)b;
  __hip_atomic_store((unsigned*)p, pk.u, __ATOMIC_RELAXED, __HIP_MEMORY_SCOPE_AGENT);
}
__device__ inline void cstore64(_Float16* p, u64 v) {
  __hip_atomic_store((u64*)p, v, __ATOMIC_RELAXED, __HIP_MEMORY_SCOPE_AGENT);
}
__device__ inline u64 cload64(const _Float16* p) {
  return __hip_atomic_load((const u64*)p, __ATOMIC_RELAXED, __HIP_MEMORY_SCOPE_AGENT);
}
__device__ inline half8 cload_h8(const _Float16* p) {
  union { u64 u[2]; half8 v; } r;
  r.u[0] = cload64(p);
  r.u[1] = cload64(p + 4);
  return r.v;
}

// R10-proven coalesced fragment-linear load: 16 frags, one waitcnt.
// b0 = snapshot_base + wv*16384 + lane*16 (bytes).
__device__ inline void ldfrag16(const char* b0, half8 (&r)[16]) {
  const char* b1 = b0 + 4096;
  const char* b2 = b0 + 8192;
  const char* b3 = b0 + 12288;
  floatx4 t0, t1, t2, t3, t4, t5, t6, t7, t8, t9, t10, t11, t12, t13, t14, t15;
  asm volatile(
      "global_load_dwordx4 %0, %16, off sc0 sc1\n\t"
      "global_load_dwordx4 %1, %16, off offset:1024 sc0 sc1\n\t"
      "global_load_dwordx4 %2, %16, off offset:2048 sc0 sc1\n\t"
      "global_load_dwordx4 %3, %16, off offset:3072 sc0 sc1\n\t"
      "global_load_dwordx4 %4, %17, off sc0 sc1\n\t"
      "global_load_dwordx4 %5, %17, off offset:1024 sc0 sc1\n\t"
      "global_load_dwordx4 %6, %17, off offset:2048 sc0 sc1\n\t"
      "global_load_dwordx4 %7, %17, off offset:3072 sc0 sc1\n\t"
      "global_load_dwordx4 %8, %18, off sc0 sc1\n\t"
      "global_load_dwordx4 %9, %18, off offset:1024 sc0 sc1\n\t"
      "global_load_dwordx4 %10, %18, off offset:2048 sc0 sc1\n\t"
      "global_load_dwordx4 %11, %18, off offset:3072 sc0 sc1\n\t"
      "global_load_dwordx4 %12, %19, off sc0 sc1\n\t"
      "global_load_dwordx4 %13, %19, off offset:1024 sc0 sc1\n\t"
      "global_load_dwordx4 %14, %19, off offset:2048 sc0 sc1\n\t"
      "global_load_dwordx4 %15, %19, off offset:3072 sc0 sc1\n\t"
      "s_waitcnt vmcnt(0)"
      : "=&v"(t0), "=&v"(t1), "=&v"(t2), "=&v"(t3),
        "=&v"(t4), "=&v"(t5), "=&v"(t6), "=&v"(t7),
        "=&v"(t8), "=&v"(t9), "=&v"(t10), "=&v"(t11),
        "=&v"(t12), "=&v"(t13), "=&v"(t14), "=&v"(t15)
      : "v"(b0), "v"(b1), "v"(b2), "v"(b3)
      : "memory");
  r[0] = __builtin_bit_cast(half8, t0);   r[1] = __builtin_bit_cast(half8, t1);
  r[2] = __builtin_bit_cast(half8, t2);   r[3] = __builtin_bit_cast(half8, t3);
  r[4] = __builtin_bit_cast(half8, t4);   r[5] = __builtin_bit_cast(half8, t5);
  r[6] = __builtin_bit_cast(half8, t6);   r[7] = __builtin_bit_cast(half8, t7);
  r[8] = __builtin_bit_cast(half8, t8);   r[9] = __builtin_bit_cast(half8, t9);
  r[10] = __builtin_bit_cast(half8, t10); r[11] = __builtin_bit_cast(half8, t11);
  r[12] = __builtin_bit_cast(half8, t12); r[13] = __builtin_bit_cast(half8, t13);
  r[14] = __builtin_bit_cast(half8, t14); r[15] = __builtin_bit_cast(half8, t15);
}

// Per-wave fresh wait: lane i polls block i's wave-wv sub-flag (1 dword).
__device__ inline void waitpw(const unsigned* p, unsigned tg) {
  if (tg == 0) return;
  int it = 0;
  for (;;) {
    unsigned v;
    asm volatile("global_load_dword %0, %1, off sc0 sc1\n\t"
                 "s_waitcnt vmcnt(0)"
                 : "=&v"(v) : "v"(p) : "memory");
    if (__all((int)(v >= tg))) return;
    if (++it > 4) __builtin_amdgcn_s_sleep(1);
  }
}

// Epilogue-only block-level wait (min over all 4 sub-flags).
__device__ inline void waitf4(const unsigned* fg, unsigned tg) {
  const unsigned* p = fg + (threadIdx.x & 63) * 32;
  int it = 0;
  for (;;) {
    floatx4 t;
    asm volatile("global_load_dwordx4 %0, %1, off sc0 sc1\n\t"
                 "s_waitcnt vmcnt(0)"
                 : "=&v"(t) : "v"(p) : "memory");
    uintx4 u = __builtin_bit_cast(uintx4, t);
    unsigned m = umin_(umin_(u.x, u.y), umin_(u.z, u.w));
    if (__all((int)(m >= tg))) return;
    if (++it > 4) __builtin_amdgcn_s_sleep(1);
  }
}

__device__ inline floatx4 mfma16(half8 a, half8 b, floatx4 c) {
  return __builtin_amdgcn_mfma_f32_16x16x32_f16(a, b, c, 0, 0, 0);
}

__global__ void init_kernel(const float* __restrict__ x, const float* __restrict__ hc,
                            _Float16* __restrict__ x16, _Float16* __restrict__ h0b,
                            _Float16* __restrict__ h1b, unsigned* __restrict__ flagbase) {
  size_t i = (size_t)blockIdx.x * blockDim.x + threadIdx.x;
  size_t stride = (size_t)gridDim.x * blockDim.x;
  // x -> frag-linear fp16 (R10-proven).
  const size_t nch = (size_t)T_STEPS * 64 * 32;
  for (size_t n = i; n < nch; n += stride) {
    size_t tr = n >> 5;
    int cc = (int)(n & 31);
    int row = (int)(tr & 63);
    size_t t = tr >> 6;
    const float* src = x + (tr * 256 + (size_t)cc * 8);
    floatx4 v0 = *(const floatx4*)src;
    floatx4 v1 = *(const floatx4*)(src + 4);
    half8 h;
    h[0] = (_Float16)v0.x; h[1] = (_Float16)v0.y; h[2] = (_Float16)v0.z; h[3] = (_Float16)v0.w;
    h[4] = (_Float16)v1.x; h[5] = (_Float16)v1.y; h[6] = (_Float16)v1.z; h[7] = (_Float16)v1.w;
    _Float16* dstp = x16 + t * 16384 + (size_t)(row >> 4) * 4096 +
                     (size_t)(cc >> 2) * 512 + (size_t)((row & 15) + 16 * (cc & 3)) * 8;
    *(half8*)dstp = h;
  }
  // h seeds in frag-linear layout (R10-proven).
  if (i < 8192) {
    int which = (int)(i >> 12);
    int idx = (int)(i & 4095);
    int m = idx >> 6, cc = idx & 63;
    const float* src = hc + (size_t)which * 32768 + (size_t)m * 512 + (size_t)cc * 8;
    union { u64 u[2]; half8 v; } pk;
#pragma unroll
    for (int e = 0; e < 8; ++e) pk.v[e] = (_Float16)src[e];
    _Float16* base = which ? (h1b + 32768) : (h0b + (size_t)(RING - 1) * 32768);
    _Float16* dstp = base + (size_t)(m >> 4) * 8192 + (size_t)(cc >> 2) * 512 +
                     (size_t)((m & 15) + 16 * (cc & 3)) * 8;
    cstore64(dstp, pk.u[0]);
    cstore64(dstp + 4, pk.u[1]);
  }
  if (i < 4096) {
    __hip_atomic_store(flagbase + i, 0u, __ATOMIC_RELAXED, __HIP_MEMORY_SCOPE_AGENT);
  }
}

__global__ __launch_bounds__(256, 1) void lstm_kernel(
    const _Float16* __restrict__ x16, _Float16* __restrict__ h0b, _Float16* __restrict__ h1b,
    unsigned* __restrict__ flags0, unsigned* __restrict__ flags1,
    const float* __restrict__ W_ih0, const float* __restrict__ W_hh0,
    const float* __restrict__ b_ih0, const float* __restrict__ b_hh0,
    const float* __restrict__ W_ih1, const float* __restrict__ W_hh1,
    const float* __restrict__ b_ih1, const float* __restrict__ b_hh1,
    const float* __restrict__ W_out, const float* __restrict__ b_out,
    const float* __restrict__ hc, float* __restrict__ out) {
  __shared__ __align__(16) _Float16 wlds[32 * 1032];

  const int bq = blockIdx.x;
  const bool isL0 = bq < 64;
  const int q = isL0 ? bq : bq - 64;
  const int col0 = q * 8;
  const int Ka = isL0 ? IN_DIM : HID;
  const int K = Ka + HID;
  const int WP = K + 8;
  const int layer = isL0 ? 0 : 1;
  const float* Wa = isL0 ? W_ih0 : W_ih1;
  const float* Wb = isL0 ? W_hh0 : W_hh1;
  const float* bia = isL0 ? b_ih0 : b_ih1;
  const float* bib = isL0 ? b_hh0 : b_hh1;

  for (int idx = threadIdx.x; idx < 32 * K; idx += 256) {
    int r = idx / K;
    int k = idx - r * K;
    int g = r >> 3, j = r & 7;
    int grow = g * HID + col0 + j;  // PyTorch gate order i,f,g,o
    float w = (k < Ka) ? Wa[(size_t)grow * Ka + k] : Wb[(size_t)grow * HID + (k - Ka)];
    wlds[r * WP + k] = (_Float16)w;
  }
  __syncthreads();  // the only block barrier before the epilogue

  const int lane = threadIdx.x & 63;
  const int wv = threadIdx.x >> 6;
  const int lrow = lane & 15;
  const int kq = (lane >> 4) * 8;
  const _Float16* wrow0 = wlds + lrow * WP;
  const _Float16* wrow1 = wlds + (16 + lrow) * WP;

  half8 breg0[16], breg1[16];
#pragma unroll
  for (int c = 0; c < 16; ++c) {
    breg0[c] = *(const half8*)(wrow0 + Ka + c * 32 + kq);
    breg1[c] = *(const half8*)(wrow1 + Ka + c * 32 + kq);
  }

  // Register-gate-phase constants (R8-proven mapping).
  const int bsel = lrow >> 3;
  const int jc = lrow & 7;
  const int rbase = wv * 16 + ((lane >> 4) << 2) + 2 * bsel;
  const int colg = col0 + jc;
  const float bi_ = bia[colg] + bib[colg];
  const float bf_ = bia[HID + colg] + bib[HID + colg];
  const float bg_ = bia[2 * HID + colg] + bib[2 * HID + colg];
  const float bo_ = bia[3 * HID + colg] + bib[3 * HID + colg];
  float cst0 = hc[(size_t)(2 + layer) * 32768 + (size_t)(rbase + 0) * HID + colg];
  float cst1 = hc[(size_t)(2 + layer) * 32768 + (size_t)(rbase + 1) * HID + colg];

  unsigned* myflag = (isL0 ? flags0 : flags1) + q * 32 + wv;
  const unsigned* pw0 = flags0 + lane * 32 + wv;  // per-wave gathers
  const unsigned* pw1 = flags1 + lane * 32 + wv;

  const size_t rd_off = (size_t)wv * 16384 + (size_t)lane * 16;  // bytes
  const size_t st_off = (size_t)wv * 8192 + (size_t)(q >> 2) * 512 +
                        (size_t)((rbase & 15) + ((q & 3) << 4)) * 8 + jc;  // halfwords

  bool skip0 = false;

  for (int t = 0; t < T_STEPS; ++t) {
    floatx4 acc0 = {0.f, 0.f, 0.f, 0.f};
    floatx4 acc1 = {0.f, 0.f, 0.f, 0.f};
    _Float16* dst;
    half8 f[16];

    if (isL0) {
      // Pre-issue per-wave samples: peers flags0, throttle flags1 (hidden
      // under the X phase; checked after its vmcnt).
      unsigned s0 = 0xffffffffu, s1 = 0xffffffffu;
      asm volatile("global_load_dword %0, %2, off sc0 sc1\n\t"
                   "global_load_dword %1, %3, off sc0 sc1"
                   : "=&v"(s0), "=&v"(s1)
                   : "v"(pw0), "v"(pw1) : "memory");
      // X phase.
      const _Float16* xw = x16 + (size_t)t * 16384 + (size_t)wv * 4096 + (size_t)lane * 8;
#pragma unroll
      for (int c = 0; c < 8; ++c) {
        half8 a = *(const half8*)(xw + c * 512);
        half8 b0v = *(const half8*)(wrow0 + c * 32 + kq);
        half8 b1v = *(const half8*)(wrow1 + c * 32 + kq);
        acc0 = mfma16(a, b0v, acc0);
        acc1 = mfma16(a, b1v, acc1);
      }
      asm volatile("s_waitcnt vmcnt(0)" ::: "memory");
      __builtin_amdgcn_sched_barrier(0);
      {
        const unsigned need0 = (unsigned)t;                       // peers: h0[t-1]
        const unsigned need1 = (t >= 8) ? (unsigned)(t - 7) : 0u;  // ring throttle
        int it = 0;
        while (!__all((int)((s0 >= need0) & (s1 >= need1)))) {
          if (++it > 4) __builtin_amdgcn_s_sleep(1);
          asm volatile("global_load_dword %0, %2, off sc0 sc1\n\t"
                       "global_load_dword %1, %3, off sc0 sc1\n\t"
                       "s_waitcnt vmcnt(0)"
                       : "=&v"(s0), "=&v"(s1)
                       : "v"(pw0), "v"(pw1) : "memory");
          __builtin_amdgcn_sched_barrier(0);
        }
      }
      const char* a1p = (const char*)(h0b + (size_t)((t - 1) & (RING - 1)) * 32768) + rd_off;
      ldfrag16(a1p, f);
#pragma unroll
      for (int c = 0; c < 16; ++c) {
        acc0 = mfma16(f[c], breg0[c], acc0);
        acc1 = mfma16(f[c], breg1[c], acc1);
      }
      dst = h0b + (size_t)(t & (RING - 1)) * 32768;
    } else {
      // L1 step t. Certificate for h0[t] usually observed last step (skip0).
      if (!skip0) waitpw(pw0, (unsigned)(t + 1));
      const char* a0p = (const char*)(h0b + (size_t)(t & (RING - 1)) * 32768) + rd_off;
      ldfrag16(a0p, f);  // vmcnt(0) inside also drains h1[t-1] stores
      // Piggybacked publish: h0[t] consumed AND h1[t-1] visible.
      if (lane == 0)
        __hip_atomic_store(myflag, (unsigned)(t + 1), __ATOMIC_RELAXED,
                           __HIP_MEMORY_SCOPE_AGENT);
      // Pre-issue peer-h1 + skip-flags0 samples (hidden under h0 MFMAs).
      unsigned sp = 0xffffffffu, s0 = 0xffffffffu;
      asm volatile("global_load_dword %0, %2, off sc0 sc1\n\t"
                   "global_load_dword %1, %3, off sc0 sc1"
                   : "=&v"(sp), "=&v"(s0)
                   : "v"(pw1), "v"(pw0) : "memory");
#pragma unroll
      for (int c = 0; c < 16; ++c) {
        half8 b0v = *(const half8*)(wrow0 + c * 32 + kq);
        half8 b1v = *(const half8*)(wrow1 + c * 32 + kq);
        acc0 = mfma16(f[c], b0v, acc0);
        acc1 = mfma16(f[c], b1v, acc1);
      }
      asm volatile("s_waitcnt vmcnt(0)" ::: "memory");
      __builtin_amdgcn_sched_barrier(0);
      {
        const unsigned need = (unsigned)(t + 1);  // peers' h1[t-1] visible
        int it = 0;
        while (!__all((int)(sp >= need))) {
          if (++it > 4) __builtin_amdgcn_s_sleep(1);
          asm volatile("global_load_dword %0, %2, off sc0 sc1\n\t"
                       "global_load_dword %1, %3, off sc0 sc1\n\t"
                       "s_waitcnt vmcnt(0)"
                       : "=&v"(sp), "=&v"(s0)
                       : "v"(pw1), "v"(pw0) : "memory");
          __builtin_amdgcn_sched_barrier(0);
        }
        skip0 = (bool)__all((int)(s0 >= (unsigned)(t + 2)));
      }
      const char* a1p = (const char*)(h1b + (size_t)((t - 1) & 1) * 32768) + rd_off;
      ldfrag16(a1p, f);
#pragma unroll
      for (int c = 0; c < 16; ++c) {
        acc0 = mfma16(f[c], breg0[c], acc0);
        acc1 = mfma16(f[c], breg1[c], acc1);
      }
      dst = h1b + (size_t)(t & 1) * 32768;
    }

    // ---- register gate phase (R8-proven) ----
    float s00 = __shfl_xor(bsel ? (float)acc0[0] : (float)acc0[2], 8);
    float s01 = __shfl_xor(bsel ? (float)acc0[1] : (float)acc0[3], 8);
    float s10 = __shfl_xor(bsel ? (float)acc1[0] : (float)acc1[2], 8);
    float s11 = __shfl_xor(bsel ? (float)acc1[1] : (float)acc1[3], 8);
    float hv0, hv1;
    {
      float o0 = bsel ? (float)acc0[2] : (float)acc0[0];
      float o1 = bsel ? (float)acc1[2] : (float)acc1[0];
      float gi = bsel ? s00 : o0;
      float gf = bsel ? o0 : s00;
      float gg = bsel ? s10 : o1;
      float go = bsel ? o1 : s10;
      float c = sig_f(gf + bf_) * cst0 + sig_f(gi + bi_) * tanh_f(gg + bg_);
      cst0 = c;
      hv0 = sig_f(go + bo_) * tanh_f(c);
    }
    {
      float o0 = bsel ? (float)acc0[3] : (float)acc0[1];
      float o1 = bsel ? (float)acc1[3] : (float)acc1[1];
      float gi = bsel ? s01 : o0;
      float gf = bsel ? o0 : s01;
      float gg = bsel ? s11 : o1;
      float go = bsel ? o1 : s11;
      float c = sig_f(gf + bf_) * cst1 + sig_f(gi + bi_) * tanh_f(gg + bg_);
      cst1 = c;
      hv1 = sig_f(go + bo_) * tanh_f(c);
    }
    float hx0 = __shfl_xor(hv0, 1);
    float hx1 = __shfl_xor(hv1, 1);
    if ((jc & 1) == 0) {
      _Float16* sb = dst + st_off;
      cstore_pair(sb, hv0, hx0);
      cstore_pair(sb + 8, hv1, hx1);
    }

    if (isL0) {
      // L0 keeps the R10 end-of-step drain+publish (it has ring slack).
      asm volatile("s_waitcnt vmcnt(0)" ::: "memory");
      if (lane == 0)
        __hip_atomic_store(myflag, (unsigned)(t + 1), __ATOMIC_RELAXED,
                           __HIP_MEMORY_SCOPE_AGENT);
    }
    // L1: fire-and-forget; publish happens after next step's ldfrag.
  }

  if (!isL0) {
    asm volatile("s_waitcnt vmcnt(0)" ::: "memory");  // drain h1[511] stores
    if (lane == 0)
      __hip_atomic_store(myflag, 1023u, __ATOMIC_RELAXED, __HIP_MEMORY_SCOPE_AGENT);
  } else {
    // Final linear: out[64,256] = h1[511] @ W_out^T + b_out.
    if (threadIdx.x < 64) waitf4(flags1, 1023u);
    __syncthreads();
    asm volatile("" ::: "memory");
    const int oc = q * 4 + (threadIdx.x & 3);
    const int m = threadIdx.x >> 2;
    const float* wrow = W_out + (size_t)oc * HID;
    const _Float16* hbase = h1b + 32768;  // h1[511] at parity 1, frag-linear
    float sum = 0.f;
#pragma unroll 4
    for (int hh = 0; hh < 64; ++hh) {
      const _Float16* cp = hbase + (size_t)(m >> 4) * 8192 + (size_t)(hh >> 2) * 512 +
                           (size_t)((m & 15) + 16 * (hh & 3)) * 8;
      half8 hvv = cload_h8(cp);
#pragma unroll
      for (int e = 0; e < 8; ++e) sum += (float)hvv[e] * wrow[hh * 8 + e];
    }
    out[m * 256 + oc] = sum + b_out[oc];
  }
}

extern "C" void kernel_launch(void* const* d_in, const int* in_sizes, int n_in,
                              void* d_out, int out_size, void* d_ws, size_t ws_size,
                              hipStream_t stream) {
  const float* x     = (const float*)d_in[0];
  const float* hc    = (const float*)d_in[1];
  const float* W_ih0 = (const float*)d_in[2];
  const float* W_hh0 = (const float*)d_in[3];
  const float* b_ih0 = (const float*)d_in[4];
  const float* b_hh0 = (const float*)d_in[5];
  const float* W_ih1 = (const float*)d_in[6];
  const float* W_hh1 = (const float*)d_in[7];
  const float* b_ih1 = (const float*)d_in[8];
  const float* b_hh1 = (const float*)d_in[9];
  const float* W_out = (const float*)d_in[10];
  const float* b_out = (const float*)d_in[11];
  float* out = (float*)d_out;

  char* ws = (char*)d_ws;
  _Float16* x16 = (_Float16*)ws;                              // 16 MB (frag-linear)
  _Float16* h0b = (_Float16*)(ws + 16777216);                 // 8 x 64 KB ring
  _Float16* h1b = (_Float16*)(ws + 16777216 + 8 * 65536);     // 2 x 64 KB
  unsigned* flags0 = (unsigned*)(ws + 16777216 + 10 * 65536);           // 8 KB
  unsigned* flags1 = (unsigned*)(ws + 16777216 + 10 * 65536 + 8192);    // 8 KB

  init_kernel<<<2048, 256, 0, stream>>>(x, hc, x16, h0b, h1b, flags0);
  lstm_kernel<<<128, 256, 0, stream>>>(x16, h0b, h1b, flags0, flags1,
                                       W_ih0, W_hh0, b_ih0, b_hh0,
                                       W_ih1, W_hh1, b_ih1, b_hh1,
                                       W_out, b_out, hc, out);
}

// Round 9
// 2030.008 us; speedup vs baseline: 1.6919x; 1.5399x over previous
//
#include <hip/hip_runtime.h>

typedef _Float16 half8 __attribute__((ext_vector_type(8)));
typedef float floatx4 __attribute__((ext_vector_type(4)));
typedef unsigned uintx4 __attribute__((ext_vector_type(4)));
typedef unsigned long long u64;

#define T_STEPS 512
#define IN_DIM 256
#define HID 512
#define RING 8

// ---- R13 = R10 (proven 1776us) + ONE change: L1's flags1 poll sample is
// pre-issued right after the h0 ldfrag (no waitcnt) and checked after the h0
// MFMA phase (vmcnt(0) ~100cy) instead of a fresh 1-RTT poll. Publish timing,
// semantics, wait order, barriers: R10 verbatim. Miss -> R10's waitf4_dual.

__device__ inline float sig_f(float x) { return 1.f / (1.f + __expf(-x)); }
__device__ inline float tanh_f(float x) {
  float t = __expf(-2.f * fabsf(x));
  return copysignf((1.f - t) / (1.f + t), x);
}
__device__ inline unsigned umin_(unsigned a, unsigned b) { return a < b ? a : b; }

__device__ inline void cstore_pair(_Float16* p, float a, float b) {
  union { unsigned u; _Float16 h[2]; } pk;
  pk.h[0] = (_Float16)a; pk.h[1] = (_Float16)b;
  __hip_atomic_store((unsigned*)p, pk.u, __ATOMIC_RELAXED, __HIP_MEMORY_SCOPE_AGENT);
}
__device__ inline void cstore64(_Float16* p, u64 v) {
  __hip_atomic_store((u64*)p, v, __ATOMIC_RELAXED, __HIP_MEMORY_SCOPE_AGENT);
}
__device__ inline u64 cload64(const _Float16* p) {
  return __hip_atomic_load((const u64*)p, __ATOMIC_RELAXED, __HIP_MEMORY_SCOPE_AGENT);
}
__device__ inline half8 cload_h8(const _Float16* p) {
  union { u64 u[2]; half8 v; } r;
  r.u[0] = cload64(p);
  r.u[1] = cload64(p + 4);
  return r.v;
}

// R10-proven coalesced fragment-linear load: 16 frags, one waitcnt.
// b0 = snapshot_base + wv*16384 + lane*16 (bytes).
__device__ inline void ldfrag16(const char* b0, half8 (&r)[16]) {
  const char* b1 = b0 + 4096;
  const char* b2 = b0 + 8192;
  const char* b3 = b0 + 12288;
  floatx4 t0, t1, t2, t3, t4, t5, t6, t7, t8, t9, t10, t11, t12, t13, t14, t15;
  asm volatile(
      "global_load_dwordx4 %0, %16, off sc0 sc1\n\t"
      "global_load_dwordx4 %1, %16, off offset:1024 sc0 sc1\n\t"
      "global_load_dwordx4 %2, %16, off offset:2048 sc0 sc1\n\t"
      "global_load_dwordx4 %3, %16, off offset:3072 sc0 sc1\n\t"
      "global_load_dwordx4 %4, %17, off sc0 sc1\n\t"
      "global_load_dwordx4 %5, %17, off offset:1024 sc0 sc1\n\t"
      "global_load_dwordx4 %6, %17, off offset:2048 sc0 sc1\n\t"
      "global_load_dwordx4 %7, %17, off offset:3072 sc0 sc1\n\t"
      "global_load_dwordx4 %8, %18, off sc0 sc1\n\t"
      "global_load_dwordx4 %9, %18, off offset:1024 sc0 sc1\n\t"
      "global_load_dwordx4 %10, %18, off offset:2048 sc0 sc1\n\t"
      "global_load_dwordx4 %11, %18, off offset:3072 sc0 sc1\n\t"
      "global_load_dwordx4 %12, %19, off sc0 sc1\n\t"
      "global_load_dwordx4 %13, %19, off offset:1024 sc0 sc1\n\t"
      "global_load_dwordx4 %14, %19, off offset:2048 sc0 sc1\n\t"
      "global_load_dwordx4 %15, %19, off offset:3072 sc0 sc1\n\t"
      "s_waitcnt vmcnt(0)"
      : "=&v"(t0), "=&v"(t1), "=&v"(t2), "=&v"(t3),
        "=&v"(t4), "=&v"(t5), "=&v"(t6), "=&v"(t7),
        "=&v"(t8), "=&v"(t9), "=&v"(t10), "=&v"(t11),
        "=&v"(t12), "=&v"(t13), "=&v"(t14), "=&v"(t15)
      : "v"(b0), "v"(b1), "v"(b2), "v"(b3)
      : "memory");
  r[0] = __builtin_bit_cast(half8, t0);   r[1] = __builtin_bit_cast(half8, t1);
  r[2] = __builtin_bit_cast(half8, t2);   r[3] = __builtin_bit_cast(half8, t3);
  r[4] = __builtin_bit_cast(half8, t4);   r[5] = __builtin_bit_cast(half8, t5);
  r[6] = __builtin_bit_cast(half8, t6);   r[7] = __builtin_bit_cast(half8, t7);
  r[8] = __builtin_bit_cast(half8, t8);   r[9] = __builtin_bit_cast(half8, t9);
  r[10] = __builtin_bit_cast(half8, t10); r[11] = __builtin_bit_cast(half8, t11);
  r[12] = __builtin_bit_cast(half8, t12); r[13] = __builtin_bit_cast(half8, t13);
  r[14] = __builtin_bit_cast(half8, t14); r[15] = __builtin_bit_cast(half8, t15);
}

// Block-level wait: lane i min-reduces block i's 4 per-wave sub-flags (16B).
__device__ inline void waitf4(const unsigned* fg, unsigned tg) {
  if (tg == 0) return;
  const unsigned* p = fg + (threadIdx.x & 63) * 32;
  int it = 0;
  for (;;) {
    floatx4 t;
    asm volatile("global_load_dwordx4 %0, %1, off sc0 sc1\n\t"
                 "s_waitcnt vmcnt(0)"
                 : "=&v"(t) : "v"(p) : "memory");
    uintx4 u = __builtin_bit_cast(uintx4, t);
    unsigned m = umin_(umin_(u.x, u.y), umin_(u.z, u.w));
    if (__all((int)(m >= tg))) return;
    if (++it > 4) __builtin_amdgcn_s_sleep(1);
  }
}

// Fallback fresh dual-poll (R10-proven): block until fg1>=tg1, sample fg0>=tg0.
__device__ inline bool waitf4_dual(const unsigned* fg1, unsigned tg1,
                                   const unsigned* fg0, unsigned tg0) {
  const unsigned* p1 = fg1 + (threadIdx.x & 63) * 32;
  const unsigned* p0 = fg0 + (threadIdx.x & 63) * 32;
  unsigned m1, m0v;
  int it = 0;
  for (;;) {
    floatx4 t1, t0;
    asm volatile("global_load_dwordx4 %0, %2, off sc0 sc1\n\t"
                 "global_load_dwordx4 %1, %3, off sc0 sc1\n\t"
                 "s_waitcnt vmcnt(0)"
                 : "=&v"(t1), "=&v"(t0)
                 : "v"(p1), "v"(p0)
                 : "memory");
    uintx4 u1 = __builtin_bit_cast(uintx4, t1);
    uintx4 u0 = __builtin_bit_cast(uintx4, t0);
    m1 = umin_(umin_(u1.x, u1.y), umin_(u1.z, u1.w));
    m0v = umin_(umin_(u0.x, u0.y), umin_(u0.z, u0.w));
    if (__all((int)(m1 >= tg1))) break;
    if (++it > 4) __builtin_amdgcn_s_sleep(1);
  }
  return (bool)__all((int)(m0v >= tg0));
}

__device__ inline floatx4 mfma16(half8 a, half8 b, floatx4 c) {
  return __builtin_amdgcn_mfma_f32_16x16x32_f16(a, b, c, 0, 0, 0);
}

__global__ void init_kernel(const float* __restrict__ x, const float* __restrict__ hc,
                            _Float16* __restrict__ x16, _Float16* __restrict__ h0b,
                            _Float16* __restrict__ h1b, unsigned* __restrict__ flagbase) {
  size_t i = (size_t)blockIdx.x * blockDim.x + threadIdx.x;
  size_t stride = (size_t)gridDim.x * blockDim.x;
  // x -> frag-linear fp16 (R10-proven).
  const size_t nch = (size_t)T_STEPS * 64 * 32;
  for (size_t n = i; n < nch; n += stride) {
    size_t tr = n >> 5;
    int cc = (int)(n & 31);
    int row = (int)(tr & 63);
    size_t t = tr >> 6;
    const float* src = x + (tr * 256 + (size_t)cc * 8);
    floatx4 v0 = *(const floatx4*)src;
    floatx4 v1 = *(const floatx4*)(src + 4);
    half8 h;
    h[0] = (_Float16)v0.x; h[1] = (_Float16)v0.y; h[2] = (_Float16)v0.z; h[3] = (_Float16)v0.w;
    h[4] = (_Float16)v1.x; h[5] = (_Float16)v1.y; h[6] = (_Float16)v1.z; h[7] = (_Float16)v1.w;
    _Float16* dstp = x16 + t * 16384 + (size_t)(row >> 4) * 4096 +
                     (size_t)(cc >> 2) * 512 + (size_t)((row & 15) + 16 * (cc & 3)) * 8;
    *(half8*)dstp = h;
  }
  // h seeds in frag-linear layout (R10-proven).
  if (i < 8192) {
    int which = (int)(i >> 12);
    int idx = (int)(i & 4095);
    int m = idx >> 6, cc = idx & 63;
    const float* src = hc + (size_t)which * 32768 + (size_t)m * 512 + (size_t)cc * 8;
    union { u64 u[2]; half8 v; } pk;
#pragma unroll
    for (int e = 0; e < 8; ++e) pk.v[e] = (_Float16)src[e];
    _Float16* base = which ? (h1b + 32768) : (h0b + (size_t)(RING - 1) * 32768);
    _Float16* dstp = base + (size_t)(m >> 4) * 8192 + (size_t)(cc >> 2) * 512 +
                     (size_t)((m & 15) + 16 * (cc & 3)) * 8;
    cstore64(dstp, pk.u[0]);
    cstore64(dstp + 4, pk.u[1]);
  }
  if (i < 4096) {
    __hip_atomic_store(flagbase + i, 0u, __ATOMIC_RELAXED, __HIP_MEMORY_SCOPE_AGENT);
  }
}

__global__ __launch_bounds__(256, 1) void lstm_kernel(
    const _Float16* __restrict__ x16, _Float16* __restrict__ h0b, _Float16* __restrict__ h1b,
    unsigned* __restrict__ flags0, unsigned* __restrict__ flags1,
    const float* __restrict__ W_ih0, const float* __restrict__ W_hh0,
    const float* __restrict__ b_ih0, const float* __restrict__ b_hh0,
    const float* __restrict__ W_ih1, const float* __restrict__ W_hh1,
    const float* __restrict__ b_ih1, const float* __restrict__ b_hh1,
    const float* __restrict__ W_out, const float* __restrict__ b_out,
    const float* __restrict__ hc, float* __restrict__ out) {
  __shared__ __align__(16) _Float16 wlds[32 * 1032];

  const int bq = blockIdx.x;
  const bool isL0 = bq < 64;
  const int q = isL0 ? bq : bq - 64;
  const int col0 = q * 8;
  const int Ka = isL0 ? IN_DIM : HID;
  const int K = Ka + HID;
  const int WP = K + 8;
  const int layer = isL0 ? 0 : 1;
  const float* Wa = isL0 ? W_ih0 : W_ih1;
  const float* Wb = isL0 ? W_hh0 : W_hh1;
  const float* bia = isL0 ? b_ih0 : b_ih1;
  const float* bib = isL0 ? b_hh0 : b_hh1;

  for (int idx = threadIdx.x; idx < 32 * K; idx += 256) {
    int r = idx / K;
    int k = idx - r * K;
    int g = r >> 3, j = r & 7;
    int grow = g * HID + col0 + j;  // PyTorch gate order i,f,g,o
    float w = (k < Ka) ? Wa[(size_t)grow * Ka + k] : Wb[(size_t)grow * HID + (k - Ka)];
    wlds[r * WP + k] = (_Float16)w;
  }
  __syncthreads();

  const int lane = threadIdx.x & 63;
  const int wv = threadIdx.x >> 6;
  const int lrow = lane & 15;
  const int kq = (lane >> 4) * 8;
  const _Float16* wrow0 = wlds + lrow * WP;
  const _Float16* wrow1 = wlds + (16 + lrow) * WP;

  half8 breg0[16], breg1[16];
#pragma unroll
  for (int c = 0; c < 16; ++c) {
    breg0[c] = *(const half8*)(wrow0 + Ka + c * 32 + kq);
    breg1[c] = *(const half8*)(wrow1 + Ka + c * 32 + kq);
  }

  // Register-gate-phase constants (R8-proven mapping).
  const int bsel = lrow >> 3;
  const int jc = lrow & 7;
  const int rbase = wv * 16 + ((lane >> 4) << 2) + 2 * bsel;
  const int colg = col0 + jc;
  const float bi_ = bia[colg] + bib[colg];
  const float bf_ = bia[HID + colg] + bib[HID + colg];
  const float bg_ = bia[2 * HID + colg] + bib[2 * HID + colg];
  const float bo_ = bia[3 * HID + colg] + bib[3 * HID + colg];
  float cst0 = hc[(size_t)(2 + layer) * 32768 + (size_t)(rbase + 0) * HID + colg];
  float cst1 = hc[(size_t)(2 + layer) * 32768 + (size_t)(rbase + 1) * HID + colg];

  unsigned* myflag = (isL0 ? flags0 : flags1) + q * 32 + wv;
  const unsigned* pf1s = flags1 + lane * 32;  // 16B sample addresses
  const unsigned* pf0s = flags0 + lane * 32;

  const size_t rd_off = (size_t)wv * 16384 + (size_t)lane * 16;  // bytes
  const size_t st_off = (size_t)wv * 8192 + (size_t)(q >> 2) * 512 +
                        (size_t)((rbase & 15) + ((q & 3) << 4)) * 8 + jc;  // halfwords

  bool skip0 = false;

  for (int t = 0; t < T_STEPS; ++t) {
    floatx4 acc0 = {0.f, 0.f, 0.f, 0.f};
    floatx4 acc1 = {0.f, 0.f, 0.f, 0.f};
    _Float16* dst;
    half8 f[16];

    if (isL0) {
      // X phase (plain frag-linear loads, no cross-block dep).
      const _Float16* xw = x16 + (size_t)t * 16384 + (size_t)wv * 4096 + (size_t)lane * 8;
#pragma unroll
      for (int c = 0; c < 8; ++c) {
        half8 a = *(const half8*)(xw + c * 512);
        half8 b0v = *(const half8*)(wrow0 + c * 32 + kq);
        half8 b1v = *(const half8*)(wrow1 + c * 32 + kq);
        acc0 = mfma16(a, b0v, acc0);
        acc1 = mfma16(a, b1v, acc1);
      }
      // Merged wait: wave0 -> peers' h0[t-1]; wave1 -> ring slot free.
      if (threadIdx.x < 64) waitf4(flags0, (unsigned)t);
      else if (threadIdx.x < 128) waitf4(flags1, (t >= RING) ? (unsigned)(t - RING + 1) : 0u);
      __syncthreads();
      asm volatile("" ::: "memory");
      const char* a1p = (const char*)(h0b + (size_t)((t - 1) & (RING - 1)) * 32768) + rd_off;
      ldfrag16(a1p, f);
#pragma unroll
      for (int c = 0; c < 16; ++c) {
        acc0 = mfma16(f[c], breg0[c], acc0);
        acc1 = mfma16(f[c], breg1[c], acc1);
      }
      dst = h0b + (size_t)(t & (RING - 1)) * 32768;
    } else {
      if (threadIdx.x < 64 && !skip0) waitf4(flags0, (unsigned)(t + 1));  // h0[t] ready
      __syncthreads();
      asm volatile("" ::: "memory");
      const char* a0p = (const char*)(h0b + (size_t)(t & (RING - 1)) * 32768) + rd_off;
      ldfrag16(a0p, f);
      // R13: pre-issue the flags1/flags0 sample now (no waitcnt) — serviced
      // well after peers' step-start publish became visible; checked after
      // the h0 MFMA phase (vmcnt ~100cy instead of a fresh 1-RTT poll).
      floatx4 smp1, smp0;
      asm volatile("global_load_dwordx4 %0, %2, off sc0 sc1\n\t"
                   "global_load_dwordx4 %1, %3, off sc0 sc1"
                   : "=&v"(smp1), "=&v"(smp0)
                   : "v"(pf1s), "v"(pf0s) : "memory");
#pragma unroll
      for (int c = 0; c < 16; ++c) {
        half8 b0v = *(const half8*)(wrow0 + c * 32 + kq);
        half8 b1v = *(const half8*)(wrow1 + c * 32 + kq);
        acc0 = mfma16(f[c], b0v, acc0);
        acc1 = mfma16(f[c], b1v, acc1);
      }
      if (threadIdx.x < 64) {
        asm volatile("s_waitcnt vmcnt(0)" ::: "memory");
        __builtin_amdgcn_sched_barrier(0);
        uintx4 u1 = __builtin_bit_cast(uintx4, smp1);
        uintx4 u0 = __builtin_bit_cast(uintx4, smp0);
        unsigned m1 = umin_(umin_(u1.x, u1.y), umin_(u1.z, u1.w));
        unsigned m0 = umin_(umin_(u0.x, u0.y), umin_(u0.z, u0.w));
        if (__all((int)(m1 >= (unsigned)t))) {
          skip0 = (bool)__all((int)(m0 >= (unsigned)(t + 2)));
        } else {
          skip0 = waitf4_dual(flags1, (unsigned)t, flags0, (unsigned)(t + 2));
        }
      }
      __syncthreads();
      asm volatile("" ::: "memory");
      const char* a1p = (const char*)(h1b + (size_t)((t - 1) & 1) * 32768) + rd_off;
      ldfrag16(a1p, f);
#pragma unroll
      for (int c = 0; c < 16; ++c) {
        acc0 = mfma16(f[c], breg0[c], acc0);
        acc1 = mfma16(f[c], breg1[c], acc1);
      }
      dst = h1b + (size_t)(t & 1) * 32768;
    }

    // ---- register gate phase (R8-proven) ----
    float s00 = __shfl_xor(bsel ? (float)acc0[0] : (float)acc0[2], 8);
    float s01 = __shfl_xor(bsel ? (float)acc0[1] : (float)acc0[3], 8);
    float s10 = __shfl_xor(bsel ? (float)acc1[0] : (float)acc1[2], 8);
    float s11 = __shfl_xor(bsel ? (float)acc1[1] : (float)acc1[3], 8);
    float hv0, hv1;
    {
      float o0 = bsel ? (float)acc0[2] : (float)acc0[0];
      float o1 = bsel ? (float)acc1[2] : (float)acc1[0];
      float gi = bsel ? s00 : o0;
      float gf = bsel ? o0 : s00;
      float gg = bsel ? s10 : o1;
      float go = bsel ? o1 : s10;
      float c = sig_f(gf + bf_) * cst0 + sig_f(gi + bi_) * tanh_f(gg + bg_);
      cst0 = c;
      hv0 = sig_f(go + bo_) * tanh_f(c);
    }
    {
      float o0 = bsel ? (float)acc0[3] : (float)acc0[1];
      float o1 = bsel ? (float)acc1[3] : (float)acc1[1];
      float gi = bsel ? s01 : o0;
      float gf = bsel ? o0 : s01;
      float gg = bsel ? s11 : o1;
      float go = bsel ? o1 : s11;
      float c = sig_f(gf + bf_) * cst1 + sig_f(gi + bi_) * tanh_f(gg + bg_);
      cst1 = c;
      hv1 = sig_f(go + bo_) * tanh_f(c);
    }
    float hx0 = __shfl_xor(hv0, 1);
    float hx1 = __shfl_xor(hv1, 1);
    if ((jc & 1) == 0) {
      _Float16* sb = dst + st_off;
      cstore_pair(sb, hv0, hx0);
      cstore_pair(sb + 8, hv1, hx1);
    }

    // Release: per-wave drain + per-wave sub-flag (R10-proven).
    asm volatile("s_waitcnt vmcnt(0)" ::: "memory");
    if ((threadIdx.x & 63) == 0) {
      __hip_atomic_store(myflag, (unsigned)(t + 1), __ATOMIC_RELAXED,
                         __HIP_MEMORY_SCOPE_AGENT);
    }
    asm volatile("" ::: "memory");
  }

  // Final linear on L0 blocks: out[64,256] = h1[511] @ W_out^T + b_out.
  if (isL0) {
    if (threadIdx.x < 64) waitf4(flags1, (unsigned)T_STEPS);
    __syncthreads();
    asm volatile("" ::: "memory");
    const int oc = q * 4 + (threadIdx.x & 3);
    const int m = threadIdx.x >> 2;
    const float* wrow = W_out + (size_t)oc * HID;
    const _Float16* hbase = h1b + 32768;  // h1[511] at parity 1, frag-linear
    float sum = 0.f;
#pragma unroll 4
    for (int hh = 0; hh < 64; ++hh) {
      const _Float16* cp = hbase + (size_t)(m >> 4) * 8192 + (size_t)(hh >> 2) * 512 +
                           (size_t)((m & 15) + 16 * (hh & 3)) * 8;
      half8 hvv = cload_h8(cp);
#pragma unroll
      for (int e = 0; e < 8; ++e) sum += (float)hvv[e] * wrow[hh * 8 + e];
    }
    out[m * 256 + oc] = sum + b_out[oc];
  }
}

extern "C" void kernel_launch(void* const* d_in, const int* in_sizes, int n_in,
                              void* d_out, int out_size, void* d_ws, size_t ws_size,
                              hipStream_t stream) {
  const float* x     = (const float*)d_in[0];
  const float* hc    = (const float*)d_in[1];
  const float* W_ih0 = (const float*)d_in[2];
  const float* W_hh0 = (const float*)d_in[3];
  const float* b_ih0 = (const float*)d_in[4];
  const float* b_hh0 = (const float*)d_in[5];
  const float* W_ih1 = (const float*)d_in[6];
  const float* W_hh1 = (const float*)d_in[7];
  const float* b_ih1 = (const float*)d_in[8];
  const float* b_hh1 = (const float*)d_in[9];
  const float* W_out = (const float*)d_in[10];
  const float* b_out = (const float*)d_in[11];
  float* out = (float*)d_out;

  char* ws = (char*)d_ws;
  _Float16* x16 = (_Float16*)ws;                              // 16 MB (frag-linear)
  _Float16* h0b = (_Float16*)(ws + 16777216);                 // 8 x 64 KB ring
  _Float16* h1b = (_Float16*)(ws + 16777216 + 8 * 65536);     // 2 x 64 KB
  unsigned* flags0 = (unsigned*)(ws + 16777216 + 10 * 65536);           // 8 KB
  unsigned* flags1 = (unsigned*)(ws + 16777216 + 10 * 65536 + 8192);    // 8 KB

  init_kernel<<<2048, 256, 0, stream>>>(x, hc, x16, h0b, h1b, flags0);
  lstm_kernel<<<128, 256, 0, stream>>>(x16, h0b, h1b, flags0, flags1,
                                       W_ih0, W_hh0, b_ih0, b_hh0,
                                       W_ih1, W_hh1, b_ih1, b_hh1,
                                       W_out, b_out, hc, out);
}

// Round 10
// 1940.546 us; speedup vs baseline: 1.7699x; 1.0461x over previous
//
#include <hip/hip_runtime.h>

typedef _Float16 half8 __attribute__((ext_vector_type(8)));
typedef float floatx4 __attribute__((ext_vector_type(4)));
typedef unsigned uintx4 __attribute__((ext_vector_type(4)));
typedef unsigned long long u64;

#define T_STEPS 512
#define IN_DIM 256
#define HID 512
#define RING 8

// ---- R14 = R10 (proven 1776us) + wave0-ONLY pre-issued flags1 sample ----
// R13 showed the hidden-poll hit path works (fallback <10%) but issuing the
// sample from all 256 lanes 4x'd read traffic on the flag lines (which 512
// waves also write every step) and regressed. R14 issues the sample only from
// wave0 — flag traffic identical to R10, check cost ~100cy on hit instead of
// a fresh 1-RTT poll. Everything else is R10 verbatim.

__device__ inline float sig_f(float x) { return 1.f / (1.f + __expf(-x)); }
__device__ inline float tanh_f(float x) {
  float t = __expf(-2.f * fabsf(x));
  return copysignf((1.f - t) / (1.f + t), x);
}
__device__ inline unsigned umin_(unsigned a, unsigned b) { return a < b ? a : b; }

__device__ inline void cstore_pair(_Float16* p, float a, float b) {
  union { unsigned u; _Float16 h[2]; } pk;
  pk.h[0] = (_Float16)a; pk.h[1] = (_Float16)b;
  __hip_atomic_store((unsigned*)p, pk.u, __ATOMIC_RELAXED, __HIP_MEMORY_SCOPE_AGENT);
}
__device__ inline void cstore64(_Float16* p, u64 v) {
  __hip_atomic_store((u64*)p, v, __ATOMIC_RELAXED, __HIP_MEMORY_SCOPE_AGENT);
}
__device__ inline u64 cload64(const _Float16* p) {
  return __hip_atomic_load((const u64*)p, __ATOMIC_RELAXED, __HIP_MEMORY_SCOPE_AGENT);
}
__device__ inline half8 cload_h8(const _Float16* p) {
  union { u64 u[2]; half8 v; } r;
  r.u[0] = cload64(p);
  r.u[1] = cload64(p + 4);
  return r.v;
}

// R10-proven coalesced fragment-linear load: 16 frags, one waitcnt.
// b0 = snapshot_base + wv*16384 + lane*16 (bytes).
__device__ inline void ldfrag16(const char* b0, half8 (&r)[16]) {
  const char* b1 = b0 + 4096;
  const char* b2 = b0 + 8192;
  const char* b3 = b0 + 12288;
  floatx4 t0, t1, t2, t3, t4, t5, t6, t7, t8, t9, t10, t11, t12, t13, t14, t15;
  asm volatile(
      "global_load_dwordx4 %0, %16, off sc0 sc1\n\t"
      "global_load_dwordx4 %1, %16, off offset:1024 sc0 sc1\n\t"
      "global_load_dwordx4 %2, %16, off offset:2048 sc0 sc1\n\t"
      "global_load_dwordx4 %3, %16, off offset:3072 sc0 sc1\n\t"
      "global_load_dwordx4 %4, %17, off sc0 sc1\n\t"
      "global_load_dwordx4 %5, %17, off offset:1024 sc0 sc1\n\t"
      "global_load_dwordx4 %6, %17, off offset:2048 sc0 sc1\n\t"
      "global_load_dwordx4 %7, %17, off offset:3072 sc0 sc1\n\t"
      "global_load_dwordx4 %8, %18, off sc0 sc1\n\t"
      "global_load_dwordx4 %9, %18, off offset:1024 sc0 sc1\n\t"
      "global_load_dwordx4 %10, %18, off offset:2048 sc0 sc1\n\t"
      "global_load_dwordx4 %11, %18, off offset:3072 sc0 sc1\n\t"
      "global_load_dwordx4 %12, %19, off sc0 sc1\n\t"
      "global_load_dwordx4 %13, %19, off offset:1024 sc0 sc1\n\t"
      "global_load_dwordx4 %14, %19, off offset:2048 sc0 sc1\n\t"
      "global_load_dwordx4 %15, %19, off offset:3072 sc0 sc1\n\t"
      "s_waitcnt vmcnt(0)"
      : "=&v"(t0), "=&v"(t1), "=&v"(t2), "=&v"(t3),
        "=&v"(t4), "=&v"(t5), "=&v"(t6), "=&v"(t7),
        "=&v"(t8), "=&v"(t9), "=&v"(t10), "=&v"(t11),
        "=&v"(t12), "=&v"(t13), "=&v"(t14), "=&v"(t15)
      : "v"(b0), "v"(b1), "v"(b2), "v"(b3)
      : "memory");
  r[0] = __builtin_bit_cast(half8, t0);   r[1] = __builtin_bit_cast(half8, t1);
  r[2] = __builtin_bit_cast(half8, t2);   r[3] = __builtin_bit_cast(half8, t3);
  r[4] = __builtin_bit_cast(half8, t4);   r[5] = __builtin_bit_cast(half8, t5);
  r[6] = __builtin_bit_cast(half8, t6);   r[7] = __builtin_bit_cast(half8, t7);
  r[8] = __builtin_bit_cast(half8, t8);   r[9] = __builtin_bit_cast(half8, t9);
  r[10] = __builtin_bit_cast(half8, t10); r[11] = __builtin_bit_cast(half8, t11);
  r[12] = __builtin_bit_cast(half8, t12); r[13] = __builtin_bit_cast(half8, t13);
  r[14] = __builtin_bit_cast(half8, t14); r[15] = __builtin_bit_cast(half8, t15);
}

// Block-level wait: lane i min-reduces block i's 4 per-wave sub-flags (16B).
__device__ inline void waitf4(const unsigned* fg, unsigned tg) {
  if (tg == 0) return;
  const unsigned* p = fg + (threadIdx.x & 63) * 32;
  int it = 0;
  for (;;) {
    floatx4 t;
    asm volatile("global_load_dwordx4 %0, %1, off sc0 sc1\n\t"
                 "s_waitcnt vmcnt(0)"
                 : "=&v"(t) : "v"(p) : "memory");
    uintx4 u = __builtin_bit_cast(uintx4, t);
    unsigned m = umin_(umin_(u.x, u.y), umin_(u.z, u.w));
    if (__all((int)(m >= tg))) return;
    if (++it > 4) __builtin_amdgcn_s_sleep(1);
  }
}

// Fallback fresh dual-poll (R10-proven): block until fg1>=tg1, sample fg0>=tg0.
__device__ inline bool waitf4_dual(const unsigned* fg1, unsigned tg1,
                                   const unsigned* fg0, unsigned tg0) {
  const unsigned* p1 = fg1 + (threadIdx.x & 63) * 32;
  const unsigned* p0 = fg0 + (threadIdx.x & 63) * 32;
  unsigned m1, m0v;
  int it = 0;
  for (;;) {
    floatx4 t1, t0;
    asm volatile("global_load_dwordx4 %0, %2, off sc0 sc1\n\t"
                 "global_load_dwordx4 %1, %3, off sc0 sc1\n\t"
                 "s_waitcnt vmcnt(0)"
                 : "=&v"(t1), "=&v"(t0)
                 : "v"(p1), "v"(p0)
                 : "memory");
    uintx4 u1 = __builtin_bit_cast(uintx4, t1);
    uintx4 u0 = __builtin_bit_cast(uintx4, t0);
    m1 = umin_(umin_(u1.x, u1.y), umin_(u1.z, u1.w));
    m0v = umin_(umin_(u0.x, u0.y), umin_(u0.z, u0.w));
    if (__all((int)(m1 >= tg1))) break;
    if (++it > 4) __builtin_amdgcn_s_sleep(1);
  }
  return (bool)__all((int)(m0v >= tg0));
}

__device__ inline floatx4 mfma16(half8 a, half8 b, floatx4 c) {
  return __builtin_amdgcn_mfma_f32_16x16x32_f16(a, b, c, 0, 0, 0);
}

__global__ void init_kernel(const float* __restrict__ x, const float* __restrict__ hc,
                            _Float16* __restrict__ x16, _Float16* __restrict__ h0b,
                            _Float16* __restrict__ h1b, unsigned* __restrict__ flagbase) {
  size_t i = (size_t)blockIdx.x * blockDim.x + threadIdx.x;
  size_t stride = (size_t)gridDim.x * blockDim.x;
  // x -> frag-linear fp16 (R10-proven).
  const size_t nch = (size_t)T_STEPS * 64 * 32;
  for (size_t n = i; n < nch; n += stride) {
    size_t tr = n >> 5;
    int cc = (int)(n & 31);
    int row = (int)(tr & 63);
    size_t t = tr >> 6;
    const float* src = x + (tr * 256 + (size_t)cc * 8);
    floatx4 v0 = *(const floatx4*)src;
    floatx4 v1 = *(const floatx4*)(src + 4);
    half8 h;
    h[0] = (_Float16)v0.x; h[1] = (_Float16)v0.y; h[2] = (_Float16)v0.z; h[3] = (_Float16)v0.w;
    h[4] = (_Float16)v1.x; h[5] = (_Float16)v1.y; h[6] = (_Float16)v1.z; h[7] = (_Float16)v1.w;
    _Float16* dstp = x16 + t * 16384 + (size_t)(row >> 4) * 4096 +
                     (size_t)(cc >> 2) * 512 + (size_t)((row & 15) + 16 * (cc & 3)) * 8;
    *(half8*)dstp = h;
  }
  // h seeds in frag-linear layout (R10-proven).
  if (i < 8192) {
    int which = (int)(i >> 12);
    int idx = (int)(i & 4095);
    int m = idx >> 6, cc = idx & 63;
    const float* src = hc + (size_t)which * 32768 + (size_t)m * 512 + (size_t)cc * 8;
    union { u64 u[2]; half8 v; } pk;
#pragma unroll
    for (int e = 0; e < 8; ++e) pk.v[e] = (_Float16)src[e];
    _Float16* base = which ? (h1b + 32768) : (h0b + (size_t)(RING - 1) * 32768);
    _Float16* dstp = base + (size_t)(m >> 4) * 8192 + (size_t)(cc >> 2) * 512 +
                     (size_t)((m & 15) + 16 * (cc & 3)) * 8;
    cstore64(dstp, pk.u[0]);
    cstore64(dstp + 4, pk.u[1]);
  }
  if (i < 4096) {
    __hip_atomic_store(flagbase + i, 0u, __ATOMIC_RELAXED, __HIP_MEMORY_SCOPE_AGENT);
  }
}

__global__ __launch_bounds__(256, 1) void lstm_kernel(
    const _Float16* __restrict__ x16, _Float16* __restrict__ h0b, _Float16* __restrict__ h1b,
    unsigned* __restrict__ flags0, unsigned* __restrict__ flags1,
    const float* __restrict__ W_ih0, const float* __restrict__ W_hh0,
    const float* __restrict__ b_ih0, const float* __restrict__ b_hh0,
    const float* __restrict__ W_ih1, const float* __restrict__ W_hh1,
    const float* __restrict__ b_ih1, const float* __restrict__ b_hh1,
    const float* __restrict__ W_out, const float* __restrict__ b_out,
    const float* __restrict__ hc, float* __restrict__ out) {
  __shared__ __align__(16) _Float16 wlds[32 * 1032];

  const int bq = blockIdx.x;
  const bool isL0 = bq < 64;
  const int q = isL0 ? bq : bq - 64;
  const int col0 = q * 8;
  const int Ka = isL0 ? IN_DIM : HID;
  const int K = Ka + HID;
  const int WP = K + 8;
  const int layer = isL0 ? 0 : 1;
  const float* Wa = isL0 ? W_ih0 : W_ih1;
  const float* Wb = isL0 ? W_hh0 : W_hh1;
  const float* bia = isL0 ? b_ih0 : b_ih1;
  const float* bib = isL0 ? b_hh0 : b_hh1;

  for (int idx = threadIdx.x; idx < 32 * K; idx += 256) {
    int r = idx / K;
    int k = idx - r * K;
    int g = r >> 3, j = r & 7;
    int grow = g * HID + col0 + j;  // PyTorch gate order i,f,g,o
    float w = (k < Ka) ? Wa[(size_t)grow * Ka + k] : Wb[(size_t)grow * HID + (k - Ka)];
    wlds[r * WP + k] = (_Float16)w;
  }
  __syncthreads();

  const int lane = threadIdx.x & 63;
  const int wv = threadIdx.x >> 6;
  const int lrow = lane & 15;
  const int kq = (lane >> 4) * 8;
  const _Float16* wrow0 = wlds + lrow * WP;
  const _Float16* wrow1 = wlds + (16 + lrow) * WP;

  half8 breg0[16], breg1[16];
#pragma unroll
  for (int c = 0; c < 16; ++c) {
    breg0[c] = *(const half8*)(wrow0 + Ka + c * 32 + kq);
    breg1[c] = *(const half8*)(wrow1 + Ka + c * 32 + kq);
  }

  // Register-gate-phase constants (R8-proven mapping).
  const int bsel = lrow >> 3;
  const int jc = lrow & 7;
  const int rbase = wv * 16 + ((lane >> 4) << 2) + 2 * bsel;
  const int colg = col0 + jc;
  const float bi_ = bia[colg] + bib[colg];
  const float bf_ = bia[HID + colg] + bib[HID + colg];
  const float bg_ = bia[2 * HID + colg] + bib[2 * HID + colg];
  const float bo_ = bia[3 * HID + colg] + bib[3 * HID + colg];
  float cst0 = hc[(size_t)(2 + layer) * 32768 + (size_t)(rbase + 0) * HID + colg];
  float cst1 = hc[(size_t)(2 + layer) * 32768 + (size_t)(rbase + 1) * HID + colg];

  unsigned* myflag = (isL0 ? flags0 : flags1) + q * 32 + wv;
  const unsigned* pf1s = flags1 + lane * 32;  // 16B sample addresses (wave0 use)
  const unsigned* pf0s = flags0 + lane * 32;

  const size_t rd_off = (size_t)wv * 16384 + (size_t)lane * 16;  // bytes
  const size_t st_off = (size_t)wv * 8192 + (size_t)(q >> 2) * 512 +
                        (size_t)((rbase & 15) + ((q & 3) << 4)) * 8 + jc;  // halfwords

  bool skip0 = false;

  for (int t = 0; t < T_STEPS; ++t) {
    floatx4 acc0 = {0.f, 0.f, 0.f, 0.f};
    floatx4 acc1 = {0.f, 0.f, 0.f, 0.f};
    _Float16* dst;
    half8 f[16];

    if (isL0) {
      // X phase (plain frag-linear loads, no cross-block dep).
      const _Float16* xw = x16 + (size_t)t * 16384 + (size_t)wv * 4096 + (size_t)lane * 8;
#pragma unroll
      for (int c = 0; c < 8; ++c) {
        half8 a = *(const half8*)(xw + c * 512);
        half8 b0v = *(const half8*)(wrow0 + c * 32 + kq);
        half8 b1v = *(const half8*)(wrow1 + c * 32 + kq);
        acc0 = mfma16(a, b0v, acc0);
        acc1 = mfma16(a, b1v, acc1);
      }
      // Merged wait: wave0 -> peers' h0[t-1]; wave1 -> ring slot free.
      if (threadIdx.x < 64) waitf4(flags0, (unsigned)t);
      else if (threadIdx.x < 128) waitf4(flags1, (t >= RING) ? (unsigned)(t - RING + 1) : 0u);
      __syncthreads();
      asm volatile("" ::: "memory");
      const char* a1p = (const char*)(h0b + (size_t)((t - 1) & (RING - 1)) * 32768) + rd_off;
      ldfrag16(a1p, f);
#pragma unroll
      for (int c = 0; c < 16; ++c) {
        acc0 = mfma16(f[c], breg0[c], acc0);
        acc1 = mfma16(f[c], breg1[c], acc1);
      }
      dst = h0b + (size_t)(t & (RING - 1)) * 32768;
    } else {
      if (threadIdx.x < 64 && !skip0) waitf4(flags0, (unsigned)(t + 1));  // h0[t] ready
      __syncthreads();
      asm volatile("" ::: "memory");
      const char* a0p = (const char*)(h0b + (size_t)(t & (RING - 1)) * 32768) + rd_off;
      ldfrag16(a0p, f);
      // R14: wave0 ONLY pre-issues the flags1/flags0 sample (no waitcnt);
      // checked after the h0 MFMA phase. Flag-line traffic == R10.
      floatx4 smp1, smp0;
      if (threadIdx.x < 64) {
        asm volatile("global_load_dwordx4 %0, %2, off sc0 sc1\n\t"
                     "global_load_dwordx4 %1, %3, off sc0 sc1"
                     : "=&v"(smp1), "=&v"(smp0)
                     : "v"(pf1s), "v"(pf0s) : "memory");
      }
#pragma unroll
      for (int c = 0; c < 16; ++c) {
        half8 b0v = *(const half8*)(wrow0 + c * 32 + kq);
        half8 b1v = *(const half8*)(wrow1 + c * 32 + kq);
        acc0 = mfma16(f[c], b0v, acc0);
        acc1 = mfma16(f[c], b1v, acc1);
      }
      if (threadIdx.x < 64) {
        asm volatile("s_waitcnt vmcnt(0)" ::: "memory");
        __builtin_amdgcn_sched_barrier(0);
        uintx4 u1 = __builtin_bit_cast(uintx4, smp1);
        uintx4 u0 = __builtin_bit_cast(uintx4, smp0);
        unsigned m1 = umin_(umin_(u1.x, u1.y), umin_(u1.z, u1.w));
        unsigned m0 = umin_(umin_(u0.x, u0.y), umin_(u0.z, u0.w));
        if (__all((int)(m1 >= (unsigned)t))) {
          skip0 = (bool)__all((int)(m0 >= (unsigned)(t + 2)));
        } else {
          skip0 = waitf4_dual(flags1, (unsigned)t, flags0, (unsigned)(t + 2));
        }
      }
      __syncthreads();
      asm volatile("" ::: "memory");
      const char* a1p = (const char*)(h1b + (size_t)((t - 1) & 1) * 32768) + rd_off;
      ldfrag16(a1p, f);
#pragma unroll
      for (int c = 0; c < 16; ++c) {
        acc0 = mfma16(f[c], breg0[c], acc0);
        acc1 = mfma16(f[c], breg1[c], acc1);
      }
      dst = h1b + (size_t)(t & 1) * 32768;
    }

    // ---- register gate phase (R8-proven) ----
    float s00 = __shfl_xor(bsel ? (float)acc0[0] : (float)acc0[2], 8);
    float s01 = __shfl_xor(bsel ? (float)acc0[1] : (float)acc0[3], 8);
    float s10 = __shfl_xor(bsel ? (float)acc1[0] : (float)acc1[2], 8);
    float s11 = __shfl_xor(bsel ? (float)acc1[1] : (float)acc1[3], 8);
    float hv0, hv1;
    {
      float o0 = bsel ? (float)acc0[2] : (float)acc0[0];
      float o1 = bsel ? (float)acc1[2] : (float)acc1[0];
      float gi = bsel ? s00 : o0;
      float gf = bsel ? o0 : s00;
      float gg = bsel ? s10 : o1;
      float go = bsel ? o1 : s10;
      float c = sig_f(gf + bf_) * cst0 + sig_f(gi + bi_) * tanh_f(gg + bg_);
      cst0 = c;
      hv0 = sig_f(go + bo_) * tanh_f(c);
    }
    {
      float o0 = bsel ? (float)acc0[3] : (float)acc0[1];
      float o1 = bsel ? (float)acc1[3] : (float)acc1[1];
      float gi = bsel ? s01 : o0;
      float gf = bsel ? o0 : s01;
      float gg = bsel ? s11 : o1;
      float go = bsel ? o1 : s11;
      float c = sig_f(gf + bf_) * cst1 + sig_f(gi + bi_) * tanh_f(gg + bg_);
      cst1 = c;
      hv1 = sig_f(go + bo_) * tanh_f(c);
    }
    float hx0 = __shfl_xor(hv0, 1);
    float hx1 = __shfl_xor(hv1, 1);
    if ((jc & 1) == 0) {
      _Float16* sb = dst + st_off;
      cstore_pair(sb, hv0, hx0);
      cstore_pair(sb + 8, hv1, hx1);
    }

    // Release: per-wave drain + per-wave sub-flag (R10-proven).
    asm volatile("s_waitcnt vmcnt(0)" ::: "memory");
    if ((threadIdx.x & 63) == 0) {
      __hip_atomic_store(myflag, (unsigned)(t + 1), __ATOMIC_RELAXED,
                         __HIP_MEMORY_SCOPE_AGENT);
    }
    asm volatile("" ::: "memory");
  }

  // Final linear on L0 blocks: out[64,256] = h1[511] @ W_out^T + b_out.
  if (isL0) {
    if (threadIdx.x < 64) waitf4(flags1, (unsigned)T_STEPS);
    __syncthreads();
    asm volatile("" ::: "memory");
    const int oc = q * 4 + (threadIdx.x & 3);
    const int m = threadIdx.x >> 2;
    const float* wrow = W_out + (size_t)oc * HID;
    const _Float16* hbase = h1b + 32768;  // h1[511] at parity 1, frag-linear
    float sum = 0.f;
#pragma unroll 4
    for (int hh = 0; hh < 64; ++hh) {
      const _Float16* cp = hbase + (size_t)(m >> 4) * 8192 + (size_t)(hh >> 2) * 512 +
                           (size_t)((m & 15) + 16 * (hh & 3)) * 8;
      half8 hvv = cload_h8(cp);
#pragma unroll
      for (int e = 0; e < 8; ++e) sum += (float)hvv[e] * wrow[hh * 8 + e];
    }
    out[m * 256 + oc] = sum + b_out[oc];
  }
}

extern "C" void kernel_launch(void* const* d_in, const int* in_sizes, int n_in,
                              void* d_out, int out_size, void* d_ws, size_t ws_size,
                              hipStream_t stream) {
  const float* x     = (const float*)d_in[0];
  const float* hc    = (const float*)d_in[1];
  const float* W_ih0 = (const float*)d_in[2];
  const float* W_hh0 = (const float*)d_in[3];
  const float* b_ih0 = (const float*)d_in[4];
  const float* b_hh0 = (const float*)d_in[5];
  const float* W_ih1 = (const float*)d_in[6];
  const float* W_hh1 = (const float*)d_in[7];
  const float* b_ih1 = (const float*)d_in[8];
  const float* b_hh1 = (const float*)d_in[9];
  const float* W_out = (const float*)d_in[10];
  const float* b_out = (const float*)d_in[11];
  float* out = (float*)d_out;

  char* ws = (char*)d_ws;
  _Float16* x16 = (_Float16*)ws;                              // 16 MB (frag-linear)
  _Float16* h0b = (_Float16*)(ws + 16777216);                 // 8 x 64 KB ring
  _Float16* h1b = (_Float16*)(ws + 16777216 + 8 * 65536);     // 2 x 64 KB
  unsigned* flags0 = (unsigned*)(ws + 16777216 + 10 * 65536);           // 8 KB
  unsigned* flags1 = (unsigned*)(ws + 16777216 + 10 * 65536 + 8192);    // 8 KB

  init_kernel<<<2048, 256, 0, stream>>>(x, hc, x16, h0b, h1b, flags0);
  lstm_kernel<<<128, 256, 0, stream>>>(x16, h0b, h1b, flags0, flags1,
                                       W_ih0, W_hh0, b_ih0, b_hh0,
                                       W_ih1, W_hh1, b_ih1, b_hh1,
                                       W_out, b_out, hc, out);
}